// Round 6
// baseline (705.339 us; speedup 1.0000x reference)
//
#include <hip/hip_runtime.h>
#include <stdint.h>

#define GW 8192
#define GMASK 8191
#define PLANE 67108864ULL   // elements per links plane
#define TPD 128             // tiles per dim (8192/64)
#define TMASK 127
#define NTILES 16384
#define QCAP 65536          // global ring entries (ints)
#define QMASK 65535
#define WPR 128             // bitmap words per lattice row

// d_ws layout (bytes)
#define OFF_CTRL   0        // 64 ints: [0]=qhead [1]=qtail [2]=active [3]=mode
#define OFF_TFLAGS 4096     // 2048 B tile-flag bits
#define OFF_QUEUE  8192     // 256 KB ring (tile+1; 0 = empty)
#define OFF_BITMAP 270336   // 8 MB selection bitmap (256-B aligned)
#define CLEAR_BYTES 8658944 // ctrl..bitmap end

typedef unsigned long long u64;
typedef unsigned int u32;

__device__ __forceinline__ u64 aload64(const u64* p) {
    return __hip_atomic_load(p, __ATOMIC_RELAXED, __HIP_MEMORY_SCOPE_AGENT);
}
__device__ __forceinline__ int aload32(const int* p) {
    return __hip_atomic_load(p, __ATOMIC_ACQUIRE, __HIP_MEMORY_SCOPE_AGENT);
}

// ---------------- clear control+tflags+queue+bitmap --------------------------
__global__ void clear_ws_kernel(uint4* __restrict__ p, int n) {
    int i = blockIdx.x * blockDim.x + threadIdx.x;
    if (i < n) p[i] = make_uint4(0, 0, 0, 0);
}

// ---------------- init: detect links encoding + seed --------------------------
__global__ void init_kernel(const unsigned char* __restrict__ links8,
                            const int* __restrict__ seed_idx,
                            char* __restrict__ ws) {
    __shared__ int c1, c3;
    if (threadIdx.x == 0) { c1 = 0; c3 = 0; }
    __syncthreads();
    int l1 = 0, l3 = 0;
    for (int i = threadIdx.x; i < 16384; i += blockDim.x) {
        if (links8[i]) { int m = i & 3; if (m == 1) l1++; else if (m == 3) l3++; }
    }
    atomicAdd(&c1, l1);
    atomicAdd(&c3, l3);
    __syncthreads();
    if (threadIdx.x == 0) {
        int* ctrl = (int*)(ws + OFF_CTRL);
        u32* tflags = (u32*)(ws + OFF_TFLAGS);
        int* q = (int*)(ws + OFF_QUEUE);
        u64* bitmap = (u64*)(ws + OFF_BITMAP);
        // mode 0: byte-bool, 1: int32, 2: float32 (byte%4==1 nonzero <=> bool)
        ctrl[3] = (c1 > 0) ? 0 : ((c3 > 0) ? 2 : 1);
        int sr = seed_idx[0] & GMASK, sc = seed_idx[1] & GMASK;
        bitmap[(u64)sr * WPR + (sc >> 6)] = 1ull << (sc & 63);
        int t = (sr >> 6) * TPD + (sc >> 6);
        tflags[t >> 5] = 1u << (t & 31);
        q[0] = t + 1;            // +1 encoding; 0 = empty slot
        ctrl[0] = 0;             // qhead
        ctrl[1] = 1;             // qtail
        ctrl[2] = 1;             // active
    }
}

// ---------------- bit-packing helpers ----------------------------------------
__device__ __forceinline__ u32 nib4(u32 w) {
    return (((w & 0x01010101u) * 0x01020408u) >> 24) & 0xFu;
}
__device__ __forceinline__ u64 pack_row_b8(const unsigned char* p) {
    const uint4* q = (const uint4*)p;
    u64 w = 0;
#pragma unroll
    for (int i = 0; i < 4; i++) {
        uint4 v = q[i];
        u64 nb = (u64)(nib4(v.x) | (nib4(v.y) << 4) | (nib4(v.z) << 8) | (nib4(v.w) << 12));
        w |= nb << (16 * i);
    }
    return w;
}
__device__ __forceinline__ u64 pack_row_b32(const u32* p) {
    u64 w = 0;
#pragma unroll
    for (int k = 0; k < 16; k++) {
        uint4 v = ((const uint4*)p)[k];
        u64 nb = (u64)((v.x != 0) | ((v.y != 0) << 1) | ((v.z != 0) << 2) | ((v.w != 0) << 3));
        w |= nb << (4 * k);
    }
    return w;
}

// ---------------- multi-CU async tile-granular BFS ----------------------------
// Persistent waves across many CUs pop 64x64 tiles from a GLOBAL ring queue.
// All cross-wave state uses device-scope atomics (XCD-coherent). Monotone
// bitmap (atomicOr only). Re-enqueue protocol: clear tflag -> fence -> read
// bitmap; pusher: bitmap OR (completed, old consumed) -> fence -> tflag OR.
__global__ void __launch_bounds__(256)
bfs_tiles_kernel(const unsigned char* __restrict__ links8,
                 char* __restrict__ ws) {
    int* ctrl   = (int*)(ws + OFF_CTRL);     // [0]=qhead [1]=qtail [2]=active [3]=mode
    u32* tflags = (u32*)(ws + OFF_TFLAGS);
    int* q      = (int*)(ws + OFF_QUEUE);
    u64* bitmap = (u64*)(ws + OFF_BITMAP);

    const int ln = threadIdx.x & 63;
    const int mode = ctrl[3];                // written by prior kernel (stream-ordered)

    const unsigned char* p0b = links8;
    const unsigned char* p1b = links8 + PLANE;
    const u32* p0w = (const u32*)links8;
    const u32* p1w = (const u32*)(links8 + PLANE * 4);

    auto enq = [&](int t2) {
        u32 bit = 1u << (t2 & 31);
        __threadfence();                               // bitmap ORs visible first
        u32 old = atomicOr(&tflags[t2 >> 5], bit);
        if (!(old & bit)) {
            atomicAdd(&ctrl[2], 1);                    // active++ before ticket
            int pos = atomicAdd(&ctrl[1], 1) & QMASK;
            __hip_atomic_store(&q[pos], t2 + 1, __ATOMIC_RELEASE, __HIP_MEMORY_SCOPE_AGENT);
        }
    };

    long long guard = 0;
    while (true) {
        int t = -1;
        if (ln == 0) {
            while (true) {
                if (aload32(&ctrl[2]) == 0) break;                // all done
                int h  = aload32(&ctrl[0]);
                int tl = aload32(&ctrl[1]);
                if (h != tl) {
                    if (atomicCAS((u32*)&ctrl[0], (u32)h, (u32)(h + 1)) == (u32)h) {
                        int pos = h & QMASK;
                        int v;
                        long long g2 = 0;
                        while ((v = __hip_atomic_load(&q[pos], __ATOMIC_ACQUIRE,
                                                      __HIP_MEMORY_SCOPE_AGENT)) == 0) {
                            __builtin_amdgcn_s_sleep(1);          // await publish
                            if (++g2 > 10000000LL) break;
                        }
                        __hip_atomic_store(&q[pos], 0, __ATOMIC_RELEASE,
                                           __HIP_MEMORY_SCOPE_AGENT);
                        t = v - 1;
                        break;
                    }
                } else {
                    __builtin_amdgcn_s_sleep(8);                  // empty: back off
                }
                if (++guard > 200000000LL) break;                 // failsafe
            }
        }
        t = __shfl(t, 0);
        if (t < 0) break;

        const int tR = t >> 7, tC = t & TMASK;
        if (ln == 0) atomicAnd(&tflags[t >> 5], ~(1u << (t & 31)));
        __threadfence();         // clear-before-read: late pushes re-enqueue us

        const int gr = tR * 64 + ln;         // this lane's global row
        u64* wp = &bitmap[(u64)gr * WPR + tC];
        u64 loaded = aload64(wp);

        u64 l0, l1;                          // packed bonds for this row
        if (mode == 0) {
            l0 = pack_row_b8(p0b + (u64)gr * GW + tC * 64);
            l1 = pack_row_b8(p1b + (u64)gr * GW + tC * 64);
        } else {
            l0 = pack_row_b32(p0w + (u64)gr * GW + tC * 64);
            l1 = pack_row_b32(p1w + (u64)gr * GW + tC * 64);
        }

        // ---- in-tile fixpoint: Kogge-Stone run-fill, both axes ----
        u64 P0 = l1 & 0x7FFFFFFFFFFFFFFFull;          // drop boundary bond 63
        u64 P1 = P0 & (P0 >> 1);
        u64 P2 = P1 & (P1 >> 2);
        u64 P3 = P2 & (P2 >> 4);
        u64 P4 = P3 & (P3 >> 8);
        u64 P5 = P4 & (P4 >> 16);
        u64 D0 = (ln < 63) ? l0 : 0ull;
        u64 D1 = D0 & __shfl_down(D0, 1);
        u64 D2 = D1 & __shfl_down(D1, 2);
        u64 D3 = D2 & __shfl_down(D2, 4);
        u64 D4 = D3 & __shfl_down(D3, 8);
        u64 D5 = D4 & __shfl_down(D4, 16);

        u64 sel = loaded;
        while (true) {
            u64 old = sel;
            sel |= (sel & P0) << 1;  sel |= (sel >> 1)  & P0;
            sel |= (sel & P1) << 2;  sel |= (sel >> 2)  & P1;
            sel |= (sel & P2) << 4;  sel |= (sel >> 4)  & P2;
            sel |= (sel & P3) << 8;  sel |= (sel >> 8)  & P3;
            sel |= (sel & P4) << 16; sel |= (sel >> 16) & P4;
            sel |= (sel & P5) << 32; sel |= (sel >> 32) & P5;
            sel |= __shfl_up(sel & D0, 1);  sel |= __shfl_down(sel, 1)  & D0;
            sel |= __shfl_up(sel & D1, 2);  sel |= __shfl_down(sel, 2)  & D1;
            sel |= __shfl_up(sel & D2, 4);  sel |= __shfl_down(sel, 4)  & D2;
            sel |= __shfl_up(sel & D3, 8);  sel |= __shfl_down(sel, 8)  & D3;
            sel |= __shfl_up(sel & D4, 16); sel |= __shfl_down(sel, 16) & D4;
            sel |= __shfl_up(sel & D5, 32); sel |= __shfl_down(sel, 32) & D5;
            if (__ballot(sel != old) == 0ull) break;
        }

        // write back own new bits (atomicOr: never erase concurrent pushes)
        u64 newbits = sel & ~loaded;
        if (newbits) atomicOr(wp, newbits);

        // ---- boundary pushes (torus-wrapped); enqueue only on genuinely-new --
        const int c0 = tC * 64;
        bool rnew = false, lnew = false;
        if ((sel >> 63) & (l1 >> 63) & 1ull) {       // bond c0+63: push right
            u64 old = atomicOr(&bitmap[(u64)gr * WPR + ((tC + 1) & TMASK)], 1ull);
            rnew = !(old & 1ull);
        }
        {                                            // bond (gr, c0-1): push left
            u64 lcol = (u64)((c0 - 1) & GMASK);
            bool lopen = (mode == 0) ? (p1b[(u64)gr * GW + lcol] != 0)
                                     : (p1w[(u64)gr * GW + lcol] != 0);
            if ((sel & 1ull) && lopen) {
                u64 old = atomicOr(&bitmap[(u64)gr * WPR + ((tC - 1) & TMASK)], 1ull << 63);
                lnew = !(old & (1ull << 63));
            }
        }
        u64 rmask = __ballot(rnew), lmask = __ballot(lnew);

        const int ga = (tR * 64 - 1) & GMASK;        // row above tile
        bool bopen = (mode == 0) ? (p0b[(u64)ga * GW + c0 + ln] != 0)
                                 : (p0w[(u64)ga * GW + c0 + ln] != 0);
        u64 top_sel = __shfl(sel, 0);
        u64 umask = __ballot(bopen && ((top_sel >> ln) & 1));
        u64 unew = 0;
        if (ln == 0 && umask) {
            u64 old = atomicOr(&bitmap[(u64)ga * WPR + tC], umask);
            unew = umask & ~old;
        }
        u64 dmask = sel & l0;                        // valid on lane 63
        const int gb = (tR * 64 + 64) & GMASK;       // row below tile
        u64 dnew = 0;
        if (ln == 63 && dmask) {
            u64 old = atomicOr(&bitmap[(u64)gb * WPR + tC], dmask);
            dnew = dmask & ~old;
        }

        if (ln == 0  && rmask) enq(tR * TPD + ((tC + 1) & TMASK));
        if (ln == 1  && lmask) enq(tR * TPD + ((tC - 1) & TMASK));
        if (ln == 0  && unew)  enq(((tR - 1) & TMASK) * TPD + tC);
        if (ln == 63 && dnew)  enq(((tR + 1) & TMASK) * TPD + tC);

        __threadfence();                             // all pushes visible
        if (ln == 0) atomicSub(&ctrl[2], 1);         // active--
    }
}

// ---------------- expand bitmap -> int32 output (write-bound, 256 MB) --------
__global__ void writeout_kernel(const u64* __restrict__ bitmap, int4* __restrict__ out) {
    int g = blockIdx.x * blockDim.x + threadIdx.x;  // int4 index
    int site0 = g << 2;
    u64 w = bitmap[site0 >> 6];
    u32 b = (u32)(w >> (site0 & 63)) & 0xFu;
    out[g] = make_int4(b & 1, (b >> 1) & 1, (b >> 2) & 1, (b >> 3) & 1);
}

extern "C" void kernel_launch(void* const* d_in, const int* in_sizes, int n_in,
                              void* d_out, int out_size, void* d_ws, size_t ws_size,
                              hipStream_t stream) {
    const unsigned char* links = (const unsigned char*)d_in[0];
    const int* seed = (const int*)d_in[1];
    char* ws = (char*)d_ws;

    int n16 = CLEAR_BYTES / 16;   // 541184 uint4
    clear_ws_kernel<<<(n16 + 255) / 256, 256, 0, stream>>>((uint4*)ws, n16);
    init_kernel<<<1, 256, 0, stream>>>(links, seed, ws);
    bfs_tiles_kernel<<<64, 256, 0, stream>>>(links, ws);
    writeout_kernel<<<65536, 256, 0, stream>>>((const u64*)(ws + OFF_BITMAP), (int4*)d_out);
}

// Round 7
// 696.198 us; speedup vs baseline: 1.0131x; 1.0131x over previous
//
#include <hip/hip_runtime.h>
#include <stdint.h>

#define GW 8192
#define GMASK 8191
#define PLANE 67108864ULL   // elements per links plane
#define WPR 128             // bitmap u64 words per lattice row
// tiles: 64 rows x 128 cols (2 u64 words per lane-row)
#define TR_CNT 128
#define TC_CNT 64
#define TRMASK 127
#define TCMASK 63
#define NTILES 8192
#define OVF_MASK 65535      // global overflow ring entries
#define LQ_CAP 4096
#define LQ_MASK 4095

// d_ws layout (bytes)
#define OFF_CTRL   0        // ints: [0]=ovf_head [1]=ovf_tail [2]=active [3]=mode
#define OFF_TFLAGS 4096     // 1 KB tile-flag bits (8192 tiles)
#define OFF_QUEUE  8192     // 256 KB overflow ring (tile+1; 0 = empty)
#define OFF_BITMAP 270336   // 8 MB selection bitmap
#define CLEAR_BYTES 8658944

typedef unsigned long long u64;
typedef unsigned int u32;

__device__ __forceinline__ int aload32(const int* p) {
    return __hip_atomic_load(p, __ATOMIC_ACQUIRE, __HIP_MEMORY_SCOPE_AGENT);
}

__global__ void clear_ws_kernel(uint4* __restrict__ p, int n) {
    int i = blockIdx.x * blockDim.x + threadIdx.x;
    if (i < n) p[i] = make_uint4(0, 0, 0, 0);
}

// ---------------- init: detect links encoding + seed --------------------------
__global__ void init_kernel(const unsigned char* __restrict__ links8,
                            const int* __restrict__ seed_idx,
                            char* __restrict__ ws) {
    __shared__ int c1, c3;
    if (threadIdx.x == 0) { c1 = 0; c3 = 0; }
    __syncthreads();
    int l1 = 0, l3 = 0;
    for (int i = threadIdx.x; i < 16384; i += blockDim.x) {
        if (links8[i]) { int m = i & 3; if (m == 1) l1++; else if (m == 3) l3++; }
    }
    atomicAdd(&c1, l1);
    atomicAdd(&c3, l3);
    __syncthreads();
    if (threadIdx.x == 0) {
        int* ctrl = (int*)(ws + OFF_CTRL);
        u32* tflags = (u32*)(ws + OFF_TFLAGS);
        int* q = (int*)(ws + OFF_QUEUE);
        u64* bitmap = (u64*)(ws + OFF_BITMAP);
        ctrl[3] = (c1 > 0) ? 0 : ((c3 > 0) ? 2 : 1);   // byte%4==1 nonzero <=> bool
        int sr = seed_idx[0] & GMASK, sc = seed_idx[1] & GMASK;
        bitmap[(u64)sr * WPR + (sc >> 6)] = 1ull << (sc & 63);
        int t = (sr >> 6) * TC_CNT + (sc >> 7);
        tflags[t >> 5] = 1u << (t & 31);
        q[0] = t + 1;
        ctrl[0] = 0; ctrl[1] = 1; ctrl[2] = 1;
    }
}

// ---------------- bit-packing helpers ----------------------------------------
__device__ __forceinline__ u32 nib4(u32 w) {
    return (((w & 0x01010101u) * 0x01020408u) >> 24) & 0xFu;
}
__device__ __forceinline__ u64 pack_row_b8(const unsigned char* p) {
    const uint4* q = (const uint4*)p;
    u64 w = 0;
#pragma unroll
    for (int i = 0; i < 4; i++) {
        uint4 v = q[i];
        u64 nb = (u64)(nib4(v.x) | (nib4(v.y) << 4) | (nib4(v.z) << 8) | (nib4(v.w) << 12));
        w |= nb << (16 * i);
    }
    return w;
}
__device__ __forceinline__ u64 pack_row_b32(const u32* p) {
    u64 w = 0;
#pragma unroll
    for (int k = 0; k < 16; k++) {
        uint4 v = ((const uint4*)p)[k];
        u64 nb = (u64)((v.x != 0) | ((v.y != 0) << 1) | ((v.z != 0) << 2) | ((v.w != 0) << 3));
        w |= nb << (4 * k);
    }
    return w;
}

#define KS6(s, P0, P1, P2, P3, P4, P5)                         \
    s |= (s & P0) << 1;  s |= (s >> 1)  & P0;                  \
    s |= (s & P1) << 2;  s |= (s >> 2)  & P1;                  \
    s |= (s & P2) << 4;  s |= (s >> 4)  & P2;                  \
    s |= (s & P3) << 8;  s |= (s >> 8)  & P3;                  \
    s |= (s & P4) << 16; s |= (s >> 16) & P4;                  \
    s |= (s & P5) << 32; s |= (s >> 32) & P5;

#define VS6(s, D0, D1, D2, D3, D4, D5)                                     \
    s |= __shfl_up(s & D0, 1);  s |= __shfl_down(s, 1)  & D0;              \
    s |= __shfl_up(s & D1, 2);  s |= __shfl_down(s, 2)  & D1;              \
    s |= __shfl_up(s & D2, 4);  s |= __shfl_down(s, 4)  & D2;              \
    s |= __shfl_up(s & D3, 8);  s |= __shfl_down(s, 8)  & D3;              \
    s |= __shfl_up(s & D4, 16); s |= __shfl_down(s, 16) & D4;              \
    s |= __shfl_up(s & D5, 32); s |= __shfl_down(s, 32) & D5;

// ---------------- multi-block tile BFS: local LDS rings + global overflow -----
__global__ void __launch_bounds__(1024)
bfs_tiles_kernel(const unsigned char* __restrict__ links8,
                 char* __restrict__ ws) {
    int* ctrl   = (int*)(ws + OFF_CTRL);
    u32* tflags = (u32*)(ws + OFF_TFLAGS);
    int* ovq    = (int*)(ws + OFF_QUEUE);
    u64* bitmap = (u64*)(ws + OFF_BITMAP);

    volatile __shared__ unsigned short lq[LQ_CAP];
    __shared__ int s_lhead, s_ltail;

    const int tid = threadIdx.x;
    const int ln  = tid & 63;
    const int wv  = tid >> 6;

    for (int i = tid; i < LQ_CAP; i += 1024) lq[i] = 0xFFFF;
    if (tid == 0) { s_lhead = 0; s_ltail = 0; }
    __syncthreads();

    const int mode = __hip_atomic_load(&ctrl[3], __ATOMIC_RELAXED, __HIP_MEMORY_SCOPE_AGENT);
    const unsigned char* p0b = links8;
    const unsigned char* p1b = links8 + PLANE;
    const u32* p0w = (const u32*)links8;
    const u32* p1w = (const u32*)links8 + PLANE;

    // push: bitmap ORs done -> fence -> tflag claim -> active++ -> publish
    auto enq = [&](int t2) {
        u32 bit = 1u << (t2 & 31);
        __threadfence();
        u32 old = atomicOr(&tflags[t2 >> 5], bit);
        if (!(old & bit)) {
            atomicAdd(&ctrl[2], 1);
            int pend = *(volatile int*)&s_ltail - *(volatile int*)&s_lhead;
            if (pend < 12) {                                  // keep chain local
                int pos = atomicAdd(&s_ltail, 1) & LQ_MASK;
                lq[pos] = (unsigned short)t2;
            } else {                                          // spill for balance
                int pos = atomicAdd(&ctrl[1], 1) & OVF_MASK;
                __hip_atomic_store(&ovq[pos], t2 + 1, __ATOMIC_RELEASE,
                                   __HIP_MEMORY_SCOPE_AGENT);
            }
        }
    };

    long long guard = 0;
    while (true) {
        int t = -1;
        if (ln == 0) {
            while (true) {
                int h = *(volatile int*)&s_lhead, tl = *(volatile int*)&s_ltail;
                if (h != tl) {                                // local ring first
                    if (atomicCAS(&s_lhead, h, h + 1) == h) {
                        int pos = h & LQ_MASK;
                        unsigned short v; long long g2 = 0;
                        while ((v = lq[pos]) == 0xFFFF) {
                            __builtin_amdgcn_s_sleep(1);
                            if (++g2 > 4000000LL) break;
                        }
                        lq[pos] = 0xFFFF;
                        t = v; break;
                    }
                    continue;
                }
                if (__hip_atomic_load(&ctrl[2], __ATOMIC_RELAXED,
                                      __HIP_MEMORY_SCOPE_AGENT) == 0) break;
                if (wv < 2) {                                 // overflow pollers
                    int oh = aload32(&ctrl[0]), ot = aload32(&ctrl[1]);
                    if (oh != ot) {
                        if (atomicCAS((u32*)&ctrl[0], (u32)oh, (u32)(oh + 1)) == (u32)oh) {
                            int pos = oh & OVF_MASK; int v; long long g2 = 0;
                            while ((v = __hip_atomic_load(&ovq[pos], __ATOMIC_ACQUIRE,
                                                          __HIP_MEMORY_SCOPE_AGENT)) == 0) {
                                __builtin_amdgcn_s_sleep(1);
                                if (++g2 > 10000000LL) break;
                            }
                            __hip_atomic_store(&ovq[pos], 0, __ATOMIC_RELEASE,
                                               __HIP_MEMORY_SCOPE_AGENT);
                            t = v - 1; break;
                        }
                        continue;
                    }
                }
                __builtin_amdgcn_s_sleep(4);
                if (++guard > 50000000LL) break;              // failsafe
            }
        }
        t = __shfl(t, 0);
        if (t < 0) break;

        const int tR = t >> 6, tC = t & TCMASK;
        if (ln == 0) atomicAnd(&tflags[t >> 5], ~(1u << (t & 31)));
        __threadfence();          // clear-before-read: late pushes re-enqueue us

        const int gr = tR * 64 + ln;
        const int c0 = tC * 128;
        u64* wp = &bitmap[(u64)gr * WPR + tC * 2];
        u64 ld0 = __hip_atomic_load(wp,     __ATOMIC_RELAXED, __HIP_MEMORY_SCOPE_AGENT);
        u64 ld1 = __hip_atomic_load(wp + 1, __ATOMIC_RELAXED, __HIP_MEMORY_SCOPE_AGENT);

        u64 l0a, l0b, l1a, l1b;   // packed bonds: words a=[c0,c0+63], b=[c0+64,c0+127]
        if (mode == 0) {
            const unsigned char* b0 = p0b + (u64)gr * GW + c0;
            const unsigned char* b1 = p1b + (u64)gr * GW + c0;
            l0a = pack_row_b8(b0); l0b = pack_row_b8(b0 + 64);
            l1a = pack_row_b8(b1); l1b = pack_row_b8(b1 + 64);
        } else {
            const u32* b0 = p0w + (u64)gr * GW + c0;
            const u32* b1 = p1w + (u64)gr * GW + c0;
            l0a = pack_row_b32(b0); l0b = pack_row_b32(b0 + 64);
            l1a = pack_row_b32(b1); l1b = pack_row_b32(b1 + 64);
        }

        // ---- in-tile fixpoint: per-word Kogge-Stone + cross-word carry ----
        const u64 INNER = 0x7FFFFFFFFFFFFFFFull;
        u64 Pa0 = l1a & INNER, Pa1 = Pa0 & (Pa0 >> 1), Pa2 = Pa1 & (Pa1 >> 2),
            Pa3 = Pa2 & (Pa2 >> 4), Pa4 = Pa3 & (Pa3 >> 8), Pa5 = Pa4 & (Pa4 >> 16);
        u64 Pb0 = l1b & INNER, Pb1 = Pb0 & (Pb0 >> 1), Pb2 = Pb1 & (Pb1 >> 2),
            Pb3 = Pb2 & (Pb2 >> 4), Pb4 = Pb3 & (Pb3 >> 8), Pb5 = Pb4 & (Pb4 >> 16);
        u64 Da0 = (ln < 63) ? l0a : 0ull;
        u64 Da1 = Da0 & __shfl_down(Da0, 1), Da2 = Da1 & __shfl_down(Da1, 2),
            Da3 = Da2 & __shfl_down(Da2, 4), Da4 = Da3 & __shfl_down(Da3, 8),
            Da5 = Da4 & __shfl_down(Da4, 16);
        u64 Db0 = (ln < 63) ? l0b : 0ull;
        u64 Db1 = Db0 & __shfl_down(Db0, 1), Db2 = Db1 & __shfl_down(Db1, 2),
            Db3 = Db2 & __shfl_down(Db2, 4), Db4 = Db3 & __shfl_down(Db3, 8),
            Db5 = Db4 & __shfl_down(Db4, 16);
        const u64 xb = (l1a >> 63) & 1ull;    // bond col c0+63 <-> c0+64

        u64 s0 = ld0, s1 = ld1;
        while (true) {
            u64 o0 = s0, o1 = s1;
            KS6(s0, Pa0, Pa1, Pa2, Pa3, Pa4, Pa5);
            s1 |= (s0 >> 63) & xb;
            KS6(s1, Pb0, Pb1, Pb2, Pb3, Pb4, Pb5);
            s0 |= ((s1 & 1ull) & xb) << 63;
            VS6(s0, Da0, Da1, Da2, Da3, Da4, Da5);
            VS6(s1, Db0, Db1, Db2, Db3, Db4, Db5);
            if (__ballot((s0 != o0) | (s1 != o1)) == 0ull) break;
        }

        u64 nb0 = s0 & ~ld0, nb1 = s1 & ~ld1;
        if (nb0) atomicOr(wp, nb0);
        if (nb1) atomicOr(wp + 1, nb1);

        // ---- boundary pushes (torus-wrapped); enqueue only on genuinely-new --
        bool rnew = false, lnew = false;
        if ((s1 >> 63) & (l1b >> 63) & 1ull) {             // push right
            u64 old = atomicOr(&bitmap[(u64)gr * WPR + ((tC * 2 + 2) & (WPR - 1))], 1ull);
            rnew = !(old & 1ull);
        }
        {                                                  // push left
            int lcol = (c0 - 1) & GMASK;
            bool lopen = (mode == 0) ? (p1b[(u64)gr * GW + lcol] != 0)
                                     : (p1w[(u64)gr * GW + lcol] != 0);
            if ((s0 & 1ull) && lopen) {
                u64 old = atomicOr(&bitmap[(u64)gr * WPR + ((tC * 2 - 1) & (WPR - 1))],
                                   1ull << 63);
                lnew = !(old & (1ull << 63));
            }
        }
        u64 rmask = __ballot(rnew), lmask = __ballot(lnew);

        const int ga = (tR * 64 - 1) & GMASK;              // row above tile
        bool bo0 = (mode == 0) ? (p0b[(u64)ga * GW + c0 + ln] != 0)
                               : (p0w[(u64)ga * GW + c0 + ln] != 0);
        bool bo1 = (mode == 0) ? (p0b[(u64)ga * GW + c0 + 64 + ln] != 0)
                               : (p0w[(u64)ga * GW + c0 + 64 + ln] != 0);
        u64 ts0 = __shfl(s0, 0), ts1 = __shfl(s1, 0);
        u64 um0 = __ballot(bo0 && ((ts0 >> ln) & 1));
        u64 um1 = __ballot(bo1 && ((ts1 >> ln) & 1));
        u64 un = 0;
        if (ln == 0) {
            if (um0) { u64 old = atomicOr(&bitmap[(u64)ga * WPR + tC * 2],     um0); un |= um0 & ~old; }
            if (um1) { u64 old = atomicOr(&bitmap[(u64)ga * WPR + tC * 2 + 1], um1); un |= um1 & ~old; }
        }
        const int gb = (tR * 64 + 64) & GMASK;             // row below tile
        u64 dn = 0;
        if (ln == 63) {
            u64 dm0 = s0 & l0a, dm1 = s1 & l0b;
            if (dm0) { u64 old = atomicOr(&bitmap[(u64)gb * WPR + tC * 2],     dm0); dn |= dm0 & ~old; }
            if (dm1) { u64 old = atomicOr(&bitmap[(u64)gb * WPR + tC * 2 + 1], dm1); dn |= dm1 & ~old; }
        }

        if (ln == 0  && rmask) enq(tR * TC_CNT + ((tC + 1) & TCMASK));
        if (ln == 1  && lmask) enq(tR * TC_CNT + ((tC - 1) & TCMASK));
        if (ln == 0  && un)    enq(((tR - 1) & TRMASK) * TC_CNT + tC);
        if (ln == 63 && dn)    enq(((tR + 1) & TRMASK) * TC_CNT + tC);

        __threadfence();
        if (ln == 0) atomicSub(&ctrl[2], 1);               // active--
    }
}

// ---------------- expand bitmap -> int32 output (write-bound, 256 MB) --------
__global__ void writeout_kernel(const u64* __restrict__ bitmap, int4* __restrict__ out) {
    int g = blockIdx.x * blockDim.x + threadIdx.x;
    int site0 = g << 2;
    u64 w = bitmap[site0 >> 6];
    u32 b = (u32)(w >> (site0 & 63)) & 0xFu;
    out[g] = make_int4(b & 1, (b >> 1) & 1, (b >> 2) & 1, (b >> 3) & 1);
}

extern "C" void kernel_launch(void* const* d_in, const int* in_sizes, int n_in,
                              void* d_out, int out_size, void* d_ws, size_t ws_size,
                              hipStream_t stream) {
    const unsigned char* links = (const unsigned char*)d_in[0];
    const int* seed = (const int*)d_in[1];
    char* ws = (char*)d_ws;

    int n16 = CLEAR_BYTES / 16;
    clear_ws_kernel<<<(n16 + 255) / 256, 256, 0, stream>>>((uint4*)ws, n16);
    init_kernel<<<1, 256, 0, stream>>>(links, seed, ws);
    bfs_tiles_kernel<<<32, 1024, 0, stream>>>(links, ws);
    writeout_kernel<<<65536, 256, 0, stream>>>((const u64*)(ws + OFF_BITMAP), (int4*)d_out);
}

// Round 8
// 663.743 us; speedup vs baseline: 1.0627x; 1.0489x over previous
//
#include <hip/hip_runtime.h>
#include <stdint.h>

#define GW 8192
#define GMASK 8191
#define PLANE 67108864ULL   // elements per links plane
#define TPD 128             // tiles per dim (8192/64)
#define TMASK 127
#define NTILES 16384
#define QCAP 16384          // ring entries (shorts, 32 KB)
#define QMASK 16383
#define WPR 128             // bitmap words per lattice row

typedef unsigned long long u64;
typedef unsigned int u32;

// ---------------- clear the 8 MB selection bitmap in ws ----------------------
__global__ void clear_bitmap_kernel(uint4* __restrict__ p, int n) {
    int i = blockIdx.x * blockDim.x + threadIdx.x;
    if (i < n) p[i] = make_uint4(0, 0, 0, 0);
}

// ---------------- bit-packing helpers ----------------------------------------
__device__ __forceinline__ u32 nib4(u32 w) {
    return (((w & 0x01010101u) * 0x01020408u) >> 24) & 0xFu;
}
__device__ __forceinline__ u64 pack_row_b8(const unsigned char* p) {
    const uint4* q = (const uint4*)p;
    u64 w = 0;
#pragma unroll
    for (int i = 0; i < 4; i++) {
        uint4 v = q[i];
        u64 nb = (u64)(nib4(v.x) | (nib4(v.y) << 4) | (nib4(v.z) << 8) | (nib4(v.w) << 12));
        w |= nb << (16 * i);
    }
    return w;
}
__device__ __forceinline__ u64 pack_row_b32(const u32* p) {
    u64 w = 0;
#pragma unroll
    for (int k = 0; k < 16; k++) {
        uint4 v = ((const uint4*)p)[k];
        u64 nb = (u64)((v.x != 0) | ((v.y != 0) << 1) | ((v.z != 0) << 2) | ((v.w != 0) << 3));
        w |= nb << (4 * k);
    }
    return w;
}

// ---------------- single-block ASYNC tile-granular BFS ------------------------
// Best measured config (R4/R5: 661.6/662.6 us). Single block: cross-CU
// coherence traffic made every multi-block variant SLOWER (R6: 705, R7: 696).
// One wave = one 64x64 tile; tiles flow through a shared ring queue.
__global__ void __launch_bounds__(1024)
bfs_tiles_kernel(const unsigned char* __restrict__ links8,
                 const int* __restrict__ seed_idx,
                 u64* __restrict__ bitmap) {
    volatile __shared__ unsigned short q[QCAP];
    __shared__ u32 tflags[NTILES / 32];
    __shared__ int s_qhead, s_qtail, s_active, s_mode, s_c1, s_c3;

    const int tid = threadIdx.x;
    const int ln  = tid & 63;

    for (int i = tid; i < QCAP; i += 1024) q[i] = 0xFFFF;
    for (int i = tid; i < NTILES / 32; i += 1024) tflags[i] = 0;
    if (tid == 0) { s_c1 = 0; s_c3 = 0; s_qhead = 0; s_qtail = 0; s_active = 0; }
    __syncthreads();

    // ---- detect links encoding (mode 0: byte-bool, 1: int32, 2: float32) ----
    int l1c = 0, l3c = 0;
    for (int i = tid; i < 16384; i += 1024) {
        if (links8[i]) { int m = i & 3; if (m == 1) l1c++; else if (m == 3) l3c++; }
    }
    atomicAdd(&s_c1, l1c);
    atomicAdd(&s_c3, l3c);
    __syncthreads();
    if (tid == 0) {
        s_mode = (s_c1 > 0) ? 0 : ((s_c3 > 0) ? 2 : 1);
        int sr = seed_idx[0] & GMASK, sc = seed_idx[1] & GMASK;
        atomicOr(&bitmap[(u64)sr * WPR + (sc >> 6)], 1ull << (sc & 63));
        int t = (sr >> 6) * TPD + (sc >> 6);
        tflags[t >> 5] = 1u << (t & 31);
        q[0] = (unsigned short)t;
        s_qtail = 1; s_active = 1;
    }
    __syncthreads();

    const int mode = s_mode;
    const unsigned char* p0b = links8;
    const unsigned char* p1b = links8 + PLANE;
    const u32* p0w = (const u32*)links8;
    const u32* p1w = (const u32*)(links8 + PLANE * 4);

    volatile int* v_head   = (volatile int*)&s_qhead;
    volatile int* v_tail   = (volatile int*)&s_qtail;
    volatile int* v_active = (volatile int*)&s_active;

    auto enq = [&](int t2) {
        u32 bit = 1u << (t2 & 31);
        u32 old = atomicOr(&tflags[t2 >> 5], bit);
        if (!(old & bit)) {
            atomicAdd(&s_active, 1);               // before ticket: no false-zero
            int pos = atomicAdd(&s_qtail, 1) & QMASK;
            q[pos] = (unsigned short)t2;           // publish (sentinel scheme)
        }
    };

    long long guard = 0;
    while (true) {
        int t = -1;
        if (ln == 0) {
            while (true) {
                if (*v_active == 0) break;                        // all done
                int h  = *v_head;
                int tl = *v_tail;
                if (h != tl) {
                    if (atomicCAS(&s_qhead, h, h + 1) == h) {     // claim slot
                        int pos = h & QMASK;
                        unsigned short v;
                        long long g2 = 0;
                        while ((v = q[pos]) == 0xFFFF) {          // await publish
                            __builtin_amdgcn_s_sleep(1);
                            if (++g2 > 4000000LL) break;
                        }
                        q[pos] = 0xFFFF;                          // release slot
                        t = v;
                        break;
                    }
                } else {
                    __builtin_amdgcn_s_sleep(2);                  // empty: back off
                }
                if (++guard > 100000000LL) break;                 // failsafe
            }
        }
        t = __shfl(t, 0);
        if (t < 0) break;

        const int tR = t >> 7, tC = t & TMASK;
        if (ln == 0) atomicAnd(&tflags[t >> 5], ~(1u << (t & 31)));
        __threadfence_block();   // clear-before-read: late pushes re-enqueue us

        const int gr = tR * 64 + ln;         // this lane's global row
        u64* wp = &bitmap[(u64)gr * WPR + tC];
        u64 loaded = *(volatile u64*)wp;

        u64 l0, l1;                          // packed bonds for this row
        if (mode == 0) {
            l0 = pack_row_b8(p0b + (u64)gr * GW + tC * 64);
            l1 = pack_row_b8(p1b + (u64)gr * GW + tC * 64);
        } else {
            l0 = pack_row_b32(p0w + (u64)gr * GW + tC * 64);
            l1 = pack_row_b32(p1w + (u64)gr * GW + tC * 64);
        }

        // ---- in-tile fixpoint: Kogge-Stone run-fill, both axes ----
        u64 P0 = l1 & 0x7FFFFFFFFFFFFFFFull;          // drop boundary bond 63
        u64 P1 = P0 & (P0 >> 1);
        u64 P2 = P1 & (P1 >> 2);
        u64 P3 = P2 & (P2 >> 4);
        u64 P4 = P3 & (P3 >> 8);
        u64 P5 = P4 & (P4 >> 16);
        u64 D0 = (ln < 63) ? l0 : 0ull;
        u64 D1 = D0 & __shfl_down(D0, 1);
        u64 D2 = D1 & __shfl_down(D1, 2);
        u64 D3 = D2 & __shfl_down(D2, 4);
        u64 D4 = D3 & __shfl_down(D3, 8);
        u64 D5 = D4 & __shfl_down(D4, 16);

        u64 sel = loaded;
        while (true) {
            u64 old = sel;
            sel |= (sel & P0) << 1;  sel |= (sel >> 1)  & P0;
            sel |= (sel & P1) << 2;  sel |= (sel >> 2)  & P1;
            sel |= (sel & P2) << 4;  sel |= (sel >> 4)  & P2;
            sel |= (sel & P3) << 8;  sel |= (sel >> 8)  & P3;
            sel |= (sel & P4) << 16; sel |= (sel >> 16) & P4;
            sel |= (sel & P5) << 32; sel |= (sel >> 32) & P5;
            sel |= __shfl_up(sel & D0, 1);  sel |= __shfl_down(sel, 1)  & D0;
            sel |= __shfl_up(sel & D1, 2);  sel |= __shfl_down(sel, 2)  & D1;
            sel |= __shfl_up(sel & D2, 4);  sel |= __shfl_down(sel, 4)  & D2;
            sel |= __shfl_up(sel & D3, 8);  sel |= __shfl_down(sel, 8)  & D3;
            sel |= __shfl_up(sel & D4, 16); sel |= __shfl_down(sel, 16) & D4;
            sel |= __shfl_up(sel & D5, 32); sel |= __shfl_down(sel, 32) & D5;
            if (__ballot(sel != old) == 0ull) break;
        }

        // write back own new bits (atomicOr: never erase concurrent pushes)
        u64 newbits = sel & ~loaded;
        if (newbits) atomicOr(wp, newbits);

        // ---- boundary pushes (torus-wrapped); enqueue only on genuinely-new --
        const int c0 = tC * 64;
        bool rnew = false, lnew = false;
        if ((sel >> 63) & (l1 >> 63) & 1ull) {       // bond c0+63: push right
            u64 old = atomicOr(&bitmap[(u64)gr * WPR + ((tC + 1) & TMASK)], 1ull);
            rnew = !(old & 1ull);
        }
        {                                            // bond (gr, c0-1): push left
            u64 lcol = (u64)((c0 - 1) & GMASK);
            bool lopen = (mode == 0) ? (p1b[(u64)gr * GW + lcol] != 0)
                                     : (p1w[(u64)gr * GW + lcol] != 0);
            if ((sel & 1ull) && lopen) {
                u64 old = atomicOr(&bitmap[(u64)gr * WPR + ((tC - 1) & TMASK)], 1ull << 63);
                lnew = !(old & (1ull << 63));
            }
        }
        u64 rmask = __ballot(rnew), lmask = __ballot(lnew);

        const int ga = (tR * 64 - 1) & GMASK;        // row above tile
        bool bopen = (mode == 0) ? (p0b[(u64)ga * GW + c0 + ln] != 0)
                                 : (p0w[(u64)ga * GW + c0 + ln] != 0);
        u64 top_sel = __shfl(sel, 0);
        u64 umask = __ballot(bopen && ((top_sel >> ln) & 1));
        u64 unew = 0;
        if (ln == 0 && umask) {
            u64 old = atomicOr(&bitmap[(u64)ga * WPR + tC], umask);
            unew = umask & ~old;
        }
        u64 dmask = sel & l0;                        // valid on lane 63
        const int gb = (tR * 64 + 64) & GMASK;       // row below tile
        u64 dnew = 0;
        if (ln == 63 && dmask) {
            u64 old = atomicOr(&bitmap[(u64)gb * WPR + tC], dmask);
            dnew = dmask & ~old;
        }

        if (ln == 0  && rmask) enq(tR * TPD + ((tC + 1) & TMASK));
        if (ln == 1  && lmask) enq(tR * TPD + ((tC - 1) & TMASK));
        if (ln == 0  && unew)  enq(((tR - 1) & TMASK) * TPD + tC);
        if (ln == 63 && dnew)  enq(((tR + 1) & TMASK) * TPD + tC);

        if (ln == 0) atomicSub(&s_active, 1);
    }
}

// ---------------- expand bitmap -> int32 output (write-bound, 256 MB) --------
// 32 B per thread: one u64-bitmap byte -> 8 int32 sites, two dwordx4 stores.
__global__ void writeout_kernel(const u64* __restrict__ bitmap, int4* __restrict__ out) {
    int g = blockIdx.x * blockDim.x + threadIdx.x;  // 8-site group index
    int site0 = g << 3;
    u64 w = bitmap[site0 >> 6];
    u32 b = (u32)(w >> (site0 & 63)) & 0xFFu;
    out[g * 2]     = make_int4(b & 1, (b >> 1) & 1, (b >> 2) & 1, (b >> 3) & 1);
    out[g * 2 + 1] = make_int4((b >> 4) & 1, (b >> 5) & 1, (b >> 6) & 1, (b >> 7) & 1);
}

extern "C" void kernel_launch(void* const* d_in, const int* in_sizes, int n_in,
                              void* d_out, int out_size, void* d_ws, size_t ws_size,
                              hipStream_t stream) {
    const unsigned char* links = (const unsigned char*)d_in[0];
    const int* seed = (const int*)d_in[1];

    u64* bitmap = (u64*)((char*)d_ws + 4096);   // 8 MB

    clear_bitmap_kernel<<<2048, 256, 0, stream>>>((uint4*)bitmap, 524288);
    bfs_tiles_kernel<<<1, 1024, 0, stream>>>(links, seed, bitmap);
    writeout_kernel<<<32768, 256, 0, stream>>>(bitmap, (int4*)d_out);
}